// Round 3
// baseline (285.777 us; speedup 1.0000x reference)
//
#include <hip/hip_runtime.h>
#include <math.h>

// Problem: B=32, T=512, F=64, O=64.
// delta[b,t,f] = (t==0) ? 0 : in[b,t,f]-in[b,t-1,f]
// x = (delta - bn_mean) * (bn_w * rsqrt(bn_var+1e-5)) + bn_b
// enc_o = x * enc_w[o] + enc_b[o]
// LIF scan over o: h = v + (enc_o - v)/2 ; s = (h>=1) ; v = s?0:h
// out[b,o,f,t] = s   (fp32, 0/1)
//
// R3: write-locality restructure. For fixed (b,o) the [F,T] slab of the
// output is CONTIGUOUS (addr = ((b*64+o)*64+f)*512+t). Block = (b, 8-f
// slab, all t): per o-step the block writes a 16KB contiguous slab (vs
// 4KB before) before striding 128KB to the next o. 256 blocks x 512 thr
// = 1 block/CU, 8 waves/CU. Each thread owns 2 t-quads for one f.

#define B_DIM 32
#define T_DIM 512
#define F_DIM 64
#define O_DIM 64

typedef float v4f __attribute__((ext_vector_type(4)));

__global__ __launch_bounds__(512) void delta_lif_kernel(
    const float* __restrict__ in,     // [B,T,F]
    const float* __restrict__ enc_w,  // [64] (O,1)
    const float* __restrict__ enc_b,  // [64]
    const float* __restrict__ bn_w,   // [1]
    const float* __restrict__ bn_b,   // [1]
    const float* __restrict__ bn_mean,// [1]
    const float* __restrict__ bn_var, // [1]
    float* __restrict__ out)          // [B,O,F,T]
{
#pragma clang fp contract(off)
    __shared__ float sW[O_DIM];
    __shared__ float sB[O_DIM];
    const int lt = threadIdx.x;
    if (lt < O_DIM) { sW[lt] = enc_w[lt]; sB[lt] = enc_b[lt]; }
    __syncthreads();

    // BatchNorm scalars — replicate reference op order exactly.
    const float vpe  = bn_var[0] + 1e-5f;
    const float r    = (float)(1.0 / sqrt((double)vpe));
    const float inv  = bn_w[0] * r;
    const float mean = bn_mean[0];
    const float bnb  = bn_b[0];

    // block -> (b, f-group of 8); thread -> (f_local = lt>>6, t4 = lt&63
    // plus t4+64). Wave = 64 lanes, same f, consecutive t4 -> each store
    // instr covers 1KB contiguous; block's 16 stores per o cover a 16KB
    // contiguous slab.
    const int b       = blockIdx.x >> 3;
    const int fg      = blockIdx.x & 7;
    const int f_local = lt >> 6;
    const int f       = (fg << 3) + f_local;
    const int t0a     = (lt & 63) << 2;       // 0..252
    const int t0b     = t0a + 256;            // 256..508

    // input: in[b, t, f] = in[b*T*F + t*F + f]
    const float* pin = in + b * (T_DIM * F_DIM) + f;

    // quad A (t0a .. t0a+3); prev = t0a-1, except t0a==0 -> delta0 = 0
    const float a0 = pin[(t0a + 0) * F_DIM];
    const float a1 = pin[(t0a + 1) * F_DIM];
    const float a2 = pin[(t0a + 2) * F_DIM];
    const float a3 = pin[(t0a + 3) * F_DIM];
    const float ap = (t0a == 0) ? a0 : pin[(t0a - 1) * F_DIM];
    // quad B (t0b .. t0b+3); t0b >= 256 so prev always valid
    const float b0 = pin[(t0b + 0) * F_DIM];
    const float b1 = pin[(t0b + 1) * F_DIM];
    const float b2 = pin[(t0b + 2) * F_DIM];
    const float b3 = pin[(t0b + 3) * F_DIM];
    const float bp = pin[(t0b - 1) * F_DIM];

    const float x0 = ((a0 - ap) - mean) * inv + bnb;
    const float x1 = ((a1 - a0) - mean) * inv + bnb;
    const float x2 = ((a2 - a1) - mean) * inv + bnb;
    const float x3 = ((a3 - a2) - mean) * inv + bnb;
    const float x4 = ((b0 - bp) - mean) * inv + bnb;
    const float x5 = ((b1 - b0) - mean) * inv + bnb;
    const float x6 = ((b2 - b1) - mean) * inv + bnb;
    const float x7 = ((b3 - b2) - mean) * inv + bnb;

    float v0 = 0.f, v1 = 0.f, v2 = 0.f, v3 = 0.f;
    float v4 = 0.f, v5 = 0.f, v6 = 0.f, v7 = 0.f;

    // out[b,o,f,t]: base = ((b*64 + o)*64 + f)*512 + t
    float* pout = out + ((b * O_DIM) * F_DIM + f) * T_DIM;
    const int offA = t0a;          // quad A
    const int offB = t0b;          // quad B (+1KB within the f-row)

#pragma unroll 4
    for (int o = 0; o < O_DIM; ++o) {
        const float w  = sW[o];
        const float bb = sB[o];

        const float e0 = x0 * w + bb;
        const float e1 = x1 * w + bb;
        const float e2 = x2 * w + bb;
        const float e3 = x3 * w + bb;
        const float e4 = x4 * w + bb;
        const float e5 = x5 * w + bb;
        const float e6 = x6 * w + bb;
        const float e7 = x7 * w + bb;

        // h = v + (e - v)/2 ; /2 exact -> *0.5f identical
        const float h0 = v0 + (e0 - v0) * 0.5f;
        const float h1 = v1 + (e1 - v1) * 0.5f;
        const float h2 = v2 + (e2 - v2) * 0.5f;
        const float h3 = v3 + (e3 - v3) * 0.5f;
        const float h4 = v4 + (e4 - v4) * 0.5f;
        const float h5 = v5 + (e5 - v5) * 0.5f;
        const float h6 = v6 + (e6 - v6) * 0.5f;
        const float h7 = v7 + (e7 - v7) * 0.5f;

        const bool g0 = (h0 >= 1.0f);
        const bool g1 = (h1 >= 1.0f);
        const bool g2 = (h2 >= 1.0f);
        const bool g3 = (h3 >= 1.0f);
        const bool g4 = (h4 >= 1.0f);
        const bool g5 = (h5 >= 1.0f);
        const bool g6 = (h6 >= 1.0f);
        const bool g7 = (h7 >= 1.0f);

        v4f sA, sB4;
        sA.x  = g0 ? 1.0f : 0.0f;  sA.y  = g1 ? 1.0f : 0.0f;
        sA.z  = g2 ? 1.0f : 0.0f;  sA.w  = g3 ? 1.0f : 0.0f;
        sB4.x = g4 ? 1.0f : 0.0f;  sB4.y = g5 ? 1.0f : 0.0f;
        sB4.z = g6 ? 1.0f : 0.0f;  sB4.w = g7 ? 1.0f : 0.0f;

        v0 = g0 ? 0.0f : h0;  v1 = g1 ? 0.0f : h1;
        v2 = g2 ? 0.0f : h2;  v3 = g3 ? 0.0f : h3;
        v4 = g4 ? 0.0f : h4;  v5 = g5 ? 0.0f : h5;
        v6 = g6 ? 0.0f : h6;  v7 = g7 ? 0.0f : h7;

        float* po = pout + o * (F_DIM * T_DIM);
        *(v4f*)(po + offA) = sA;
        *(v4f*)(po + offB) = sB4;
    }
}

extern "C" void kernel_launch(void* const* d_in, const int* in_sizes, int n_in,
                              void* d_out, int out_size, void* d_ws, size_t ws_size,
                              hipStream_t stream) {
    const float* in      = (const float*)d_in[0];
    const float* enc_w   = (const float*)d_in[1];
    const float* enc_b   = (const float*)d_in[2];
    const float* bn_w    = (const float*)d_in[3];
    const float* bn_b    = (const float*)d_in[4];
    const float* bn_mean = (const float*)d_in[5];
    const float* bn_var  = (const float*)d_in[6];
    float* out = (float*)d_out;

    // 256 blocks (32 b x 8 f-groups) x 512 threads
    delta_lif_kernel<<<dim3(B_DIM * 8), dim3(512), 0, stream>>>(
        in, enc_w, enc_b, bn_w, bn_b, bn_mean, bn_var, out);
}

// Round 4
// 269.512 us; speedup vs baseline: 1.0604x; 1.0604x over previous
//
#include <hip/hip_runtime.h>
#include <math.h>

// Problem: B=32, T=512, F=64, O=64.
// delta[b,t,f] = (t==0) ? 0 : in[b,t,f]-in[b,t-1,f]
// x = (delta - bn_mean) * (bn_w * rsqrt(bn_var+1e-5)) + bn_b
// enc_o = x * enc_w[o] + enc_b[o]
// LIF scan over o: h = v + (enc_o - v)/2 ; s = (h>=1) ; v = s?0:h
// out[b,o,f,t] = s   (fp32, 0/1)
//
// R4: XCD-aware swizzle. Block->XCD assignment is round-robin (bid%8), so
// without swizzle each XCD's private L2 collects dirty lines from 128
// address-scattered 4KB islands per o-step and drains them unsorted to
// HBM. Swizzle vbid = (bid&7)*128 + (bid>>3) gives each XCD a CONTIGUOUS
// bf-range -> per o-step its L2 holds a few large contiguous dirty runs
// (full 128KB [F,T] slabs per b) -> sequential DRAM-row drain.
// Also: no LDS — enc_w[o]/enc_b[o] are wave-uniform loads (s_load), and
// VGPR count stays ~20 for max occupancy.

#define B_DIM 32
#define T_DIM 512
#define F_DIM 64
#define O_DIM 64

typedef float v4f __attribute__((ext_vector_type(4)));

__global__ __launch_bounds__(256) void delta_lif_kernel(
    const float* __restrict__ in,     // [B,T,F]
    const float* __restrict__ enc_w,  // [64] (O,1)
    const float* __restrict__ enc_b,  // [64]
    const float* __restrict__ bn_w,   // [1]
    const float* __restrict__ bn_b,   // [1]
    const float* __restrict__ bn_mean,// [1]
    const float* __restrict__ bn_var, // [1]
    float* __restrict__ out)          // [B,O,F,T]
{
#pragma clang fp contract(off)
    // BatchNorm scalars — replicate reference op order exactly.
    const float vpe  = bn_var[0] + 1e-5f;
    const float r    = (float)(1.0 / sqrt((double)vpe));
    const float inv  = bn_w[0] * r;
    const float mean = bn_mean[0];
    const float bnb  = bn_b[0];

    // XCD swizzle: consecutive vbid -> consecutive addresses on ONE XCD.
    const int bid  = blockIdx.x;                 // 0..1023
    const int vbid = ((bid & 7) << 7) + (bid >> 3);

    // block covers bf-pair {2*vbid, 2*vbid+1}; thread: f_idx = lt>>7,
    // t4 = lt&127. Wave = 64 consecutive t4, same f -> 1KB contiguous
    // per dwordx4 store.
    const int lt    = threadIdx.x;
    const int bf    = (vbid << 1) + (lt >> 7);
    const int t0    = (lt & 127) << 2;
    const int b     = bf >> 6;
    const int f     = bf & 63;

    // input: in[b, t, f] = in[b*T*F + t*F + f]
    const float* pin = in + b * (T_DIM * F_DIM) + f;
    const float c0 = pin[(t0 + 0) * F_DIM];
    const float c1 = pin[(t0 + 1) * F_DIM];
    const float c2 = pin[(t0 + 2) * F_DIM];
    const float c3 = pin[(t0 + 3) * F_DIM];
    const float p  = (t0 == 0) ? c0 : pin[(t0 - 1) * F_DIM];

    const float x0 = ((c0 - p)  - mean) * inv + bnb;
    const float x1 = ((c1 - c0) - mean) * inv + bnb;
    const float x2 = ((c2 - c1) - mean) * inv + bnb;
    const float x3 = ((c3 - c2) - mean) * inv + bnb;

    float v0 = 0.0f, v1 = 0.0f, v2 = 0.0f, v3 = 0.0f;

    // out[b,o,f,t] = out[(b<<21) + (o<<15) + (f<<9) + t]
    float* pout = out + (b << 21) + (f << 9) + t0;

#pragma unroll 8
    for (int o = 0; o < O_DIM; ++o) {
        // wave-uniform -> scalar loads, no LDS round-trip
        const float w  = enc_w[o];
        const float bb = enc_b[o];

        const float e0 = x0 * w + bb;
        const float e1 = x1 * w + bb;
        const float e2 = x2 * w + bb;
        const float e3 = x3 * w + bb;

        // h = v + (e - v)/2 ; /2 exact -> *0.5f identical
        const float h0 = v0 + (e0 - v0) * 0.5f;
        const float h1 = v1 + (e1 - v1) * 0.5f;
        const float h2 = v2 + (e2 - v2) * 0.5f;
        const float h3 = v3 + (e3 - v3) * 0.5f;

        const bool g0 = (h0 >= 1.0f);
        const bool g1 = (h1 >= 1.0f);
        const bool g2 = (h2 >= 1.0f);
        const bool g3 = (h3 >= 1.0f);

        v4f s;
        s.x = g0 ? 1.0f : 0.0f;
        s.y = g1 ? 1.0f : 0.0f;
        s.z = g2 ? 1.0f : 0.0f;
        s.w = g3 ? 1.0f : 0.0f;

        v0 = g0 ? 0.0f : h0;
        v1 = g1 ? 0.0f : h1;
        v2 = g2 ? 0.0f : h2;
        v3 = g3 ? 0.0f : h3;

        *(v4f*)(pout + (o << 15)) = s;
    }
}

extern "C" void kernel_launch(void* const* d_in, const int* in_sizes, int n_in,
                              void* d_out, int out_size, void* d_ws, size_t ws_size,
                              hipStream_t stream) {
    const float* in      = (const float*)d_in[0];
    const float* enc_w   = (const float*)d_in[1];
    const float* enc_b   = (const float*)d_in[2];
    const float* bn_w    = (const float*)d_in[3];
    const float* bn_b    = (const float*)d_in[4];
    const float* bn_mean = (const float*)d_in[5];
    const float* bn_var  = (const float*)d_in[6];
    float* out = (float*)d_out;

    // 1024 blocks (512 bf-pairs, XCD-swizzled) x 256 threads
    delta_lif_kernel<<<dim3(1024), dim3(256), 0, stream>>>(
        in, enc_w, enc_b, bn_w, bn_b, bn_mean, bn_var, out);
}